// Round 1
// baseline (60.345 us; speedup 1.0000x reference)
//
#include <hip/hip_runtime.h>

// Closed form derived from the circuit algebra:
//   state = ⊗_i RY(p_i) RX(x_i) |0>   (product state; gates act on disjoint wires)
//   CNOT ladder in Heisenberg picture: U† Z_i U = Z_0 Z_1 ... Z_i
//   <Z>_single(α, β) = cos(α) cos(β)  for RY(β)RX(α)|0>
//   => out[b,i] = prod_{j<=i} cos(x[b,j]) * cos(params[j])

#define NQ   10
#define BLK  64
#define PAD  (NQ + 1)   // stride 11: coprime with 32 banks -> conflict-free

__global__ __launch_bounds__(BLK)
void qsim_prefix_kernel(const float* __restrict__ x,
                        const float* __restrict__ p,
                        float* __restrict__ out,
                        int total /* batch * NQ */) {
    __shared__ float sx[BLK * PAD];
    const int t = threadIdx.x;
    const long base = (long)blockIdx.x * (BLK * NQ);

    // cos(params): 10 broadcast scalar loads, identical across lanes
    float cp[NQ];
#pragma unroll
    for (int j = 0; j < NQ; ++j) cp[j] = cosf(p[j]);

    // Coalesced global -> padded LDS (row-major rows of 10, stride 11)
#pragma unroll
    for (int k = 0; k < NQ; ++k) {
        int idx = k * BLK + t;          // 0 .. 639, coalesced
        long g = base + idx;
        if (g < total) {
            int row = idx / NQ;
            int col = idx - row * NQ;
            sx[row * PAD + col] = x[g];
        }
    }
    __syncthreads();

    // Per-row prefix product of cos(x)*cos(p); thread t owns row t.
    // Read and write only row t -> no cross-thread hazard, no sync needed
    // between the read and the in-place write below.
    float acc = 1.0f;
#pragma unroll
    for (int j = 0; j < NQ; ++j) {
        acc *= cosf(sx[t * PAD + j]) * cp[j];
        sx[t * PAD + j] = acc;          // overwrite own row with results
    }
    __syncthreads();

    // Coalesced LDS -> global store
#pragma unroll
    for (int k = 0; k < NQ; ++k) {
        int idx = k * BLK + t;
        long g = base + idx;
        if (g < total) {
            int row = idx / NQ;
            int col = idx - row * NQ;
            out[g] = sx[row * PAD + col];
        }
    }
}

extern "C" void kernel_launch(void* const* d_in, const int* in_sizes, int n_in,
                              void* d_out, int out_size, void* d_ws, size_t ws_size,
                              hipStream_t stream) {
    const float* x = (const float*)d_in[0];   // [BATCH, NQ] float32
    const float* p = (const float*)d_in[1];   // [NQ] float32
    float* out = (float*)d_out;               // [BATCH, NQ] float32

    const int total = in_sizes[0];            // BATCH * NQ = 163840
    const int batch = total / NQ;             // 16384
    const int grid = (batch + BLK - 1) / BLK; // 256 blocks, one wave each

    qsim_prefix_kernel<<<grid, BLK, 0, stream>>>(x, p, out, total);
}

// Round 2
// 56.285 us; speedup vs baseline: 1.0721x; 1.0721x over previous
//
#include <hip/hip_runtime.h>

// Closed form derived from the circuit algebra:
//   state = ⊗_i RY(p_i) RX(x_i) |0>   (product state; gates act on disjoint wires)
//   CNOT ladder in Heisenberg picture: U† Z_i U = Z_0 Z_1 ... Z_i
//   <Z>_single(α, β) = cos(α) cos(β)  for RY(β)RX(α)|0>
//   => out[b,i] = prod_{j<=i} cos(x[b,j]) * cos(params[j])
//
// Inputs are N(0,1) (|arg| < ~6), so the hardware v_cos_f32 path (__cosf,
// input scaled to revolutions) is accurate to ~1e-6 here — absmax slack vs
// the threshold is ~16x with even full-precision cos.

#define NQ   10
#define BLK  64
#define ROWS_PER_BLK  BLK                   // 1 row per thread
#define FLOATS_PER_BLK (ROWS_PER_BLK * NQ)  // 640
#define VEC4_PER_BLK   (FLOATS_PER_BLK / 4) // 160

__global__ __launch_bounds__(BLK)
void qsim_prefix_kernel(const float4* __restrict__ x4,
                        const float* __restrict__ p,
                        float4* __restrict__ out4,
                        int total_vec4) {
    __shared__ float sx[FLOATS_PER_BLK];    // unpadded: float4-contiguous
    float4* sx4 = (float4*)sx;
    const int t = threadIdx.x;
    const int vbase = blockIdx.x * VEC4_PER_BLK;

    // cos(params): 10 broadcast scalar loads (scalar-cached, uniform)
    float cp[NQ];
#pragma unroll
    for (int j = 0; j < NQ; ++j) cp[j] = __cosf(p[j]);

    // Coalesced float4 global -> LDS  (160 vec4 per block: 64+64+32 lanes)
#pragma unroll
    for (int k = 0; k < 3; ++k) {
        int idx = k * BLK + t;
        if (idx < VEC4_PER_BLK && vbase + idx < total_vec4)
            sx4[idx] = x4[vbase + idx];
    }
    __syncthreads();

    // Thread t owns row t (floats [t*10, t*10+10)). Prefix product with
    // hardware cosine. In-place overwrite of own row only -> no hazard.
    float acc = 1.0f;
#pragma unroll
    for (int j = 0; j < NQ; ++j) {
        acc *= __cosf(sx[t * NQ + j]) * cp[j];
        sx[t * NQ + j] = acc;
    }
    __syncthreads();

    // Coalesced LDS -> global float4 store
#pragma unroll
    for (int k = 0; k < 3; ++k) {
        int idx = k * BLK + t;
        if (idx < VEC4_PER_BLK && vbase + idx < total_vec4)
            out4[vbase + idx] = sx4[idx];
    }
}

extern "C" void kernel_launch(void* const* d_in, const int* in_sizes, int n_in,
                              void* d_out, int out_size, void* d_ws, size_t ws_size,
                              hipStream_t stream) {
    const float4* x4 = (const float4*)d_in[0];  // [BATCH, NQ] float32, BATCH*NQ % 4 == 0
    const float* p = (const float*)d_in[1];     // [NQ] float32
    float4* out4 = (float4*)d_out;              // [BATCH, NQ] float32

    const int total = in_sizes[0];              // BATCH * NQ = 163840
    const int batch = total / NQ;               // 16384
    const int grid = (batch + ROWS_PER_BLK - 1) / ROWS_PER_BLK;  // 256

    qsim_prefix_kernel<<<grid, BLK, 0, stream>>>(x4, p, out4, total / 4);
}